// Round 2
// baseline (134.215 us; speedup 1.0000x reference)
//
#include <hip/hip_runtime.h>

#define TPB 256

constexpr int NSEQ = 32768;
constexpr int C0   = 2048;   // output samples per block

// Analysis halos: h_l = 2*h_{l+1} + 3, h_5 = 4  ->  {221,109,53,25,11,4}
// Analysis buffer lengths LA[l] = C0/2^l + 2*h_l = {2490,1242,618,306,150,72}
// Synthesis buffers have halo 4: LS[l] = C0/2^l + 8

// gate(y) = sigmoid(10(y-b)) + sigmoid(-10(y+b))
__device__ __forceinline__ float gate(float y, float bb) {
    float e1 = __expf(-10.f * (y - bb));
    float e2 = __expf( 10.f * (y + bb));
    return __builtin_amdgcn_rcpf(1.f + e1) + __builtin_amdgcn_rcpf(1.f + e2);
}

// One analysis level: out[ch, i] = v * gate(v), v = sum_t in[ch>>1, 2i+t] * K[ch, t]
// Exact halos make the local input index simply 2i + t.
// Stores 0 outside the valid global range [0, Nlev) (reference zero-pad semantics).
template<int Lin, int Lout, int Gout, int Nlev>
__device__ __forceinline__ void analysis_step(
    const float* __restrict__ in, float* __restrict__ out,
    const float* __restrict__ kf, const float* __restrict__ bias, int outBase)
{
    constexpr int TOT = Lout * Gout;
    for (int idx = threadIdx.x; idx < TOT; idx += TPB) {
        const int ch = idx / Lout;          // compile-time magic div
        const int i  = idx - ch * Lout;
        const float* __restrict__ krow = kf + ch * 8;
        const float* __restrict__ ip   = in + (ch >> 1) * Lin + 2 * i;
        float y = 0.f;
#pragma unroll
        for (int t = 0; t < 8; ++t) y = fmaf(ip[t], krow[t], y);
        const int m = outBase + i;
        const float v = y * gate(y, bias[ch]);
        out[idx] = ((unsigned)m < (unsigned)Nlev) ? v : 0.f;
    }
}

// One synthesis level (transposed conv, stride 2, 8 taps):
// out[g, n] = sum_{c in 0,1} sum_q y[2g+c, j0+q] * K[2g+c, kb-2q]
// j0 = (nl+1)>>1, kb = 7-(nl&1); both in and out stored with halo 4.
template<int Lin, int Lout, int Gout, int Nlev>
__device__ __forceinline__ void synth_step(
    const float* __restrict__ in, float* __restrict__ out,
    const float* __restrict__ kf, int outBase)
{
    constexpr int TOT = Lout * Gout;
    for (int idx = threadIdx.x; idx < TOT; idx += TPB) {
        const int g  = idx / Lout;
        const int nl = idx - g * Lout;
        const float* __restrict__ y0 = in + (2 * g) * Lin;
        const float* __restrict__ y1 = y0 + Lin;
        const float* __restrict__ k0 = kf + (2 * g) * 8;
        const float* __restrict__ k1 = k0 + 8;
        const int j0 = (nl + 1) >> 1;
        const int kb = 7 - (nl & 1);
        float acc = 0.f;
#pragma unroll
        for (int q = 0; q < 4; ++q) {
            acc = fmaf(y0[j0 + q], k0[kb - 2 * q], acc);
            acc = fmaf(y1[j0 + q], k1[kb - 2 * q], acc);
        }
        const int n = outBase + nl;
        out[idx] = ((unsigned)n < (unsigned)Nlev) ? acc : 0.f;
    }
}

__global__ __launch_bounds__(TPB) void wpt_fused(
    const float* __restrict__ x,
    const float* __restrict__ K1, const float* __restrict__ K2,
    const float* __restrict__ K3, const float* __restrict__ K4,
    const float* __restrict__ K5,
    const float* __restrict__ B1, const float* __restrict__ B2,
    const float* __restrict__ B3, const float* __restrict__ B4,
    const float* __restrict__ B5,
    float* __restrict__ out)
{
    __shared__ float bufA[2496];
    __shared__ float bufB[2496];
    __shared__ float kf[496];   // all 62 filter rows of 8
    __shared__ float bss[62];   // all biases

    const int tid   = threadIdx.x;
    const int batch = blockIdx.x >> 4;
    const int cid   = blockIdx.x & 15;
    const int s     = cid * C0;

    // Stage filters + biases into LDS
    {
        const float* kin[5] = {K1, K2, K3, K4, K5};
        const float* bin[5] = {B1, B2, B3, B4, B5};
        const int koff[5] = {0, 16, 48, 112, 240};
        const int boff[5] = {0, 2, 6, 14, 30};
#pragma unroll
        for (int l = 0; l < 5; ++l) {
            for (int i = tid; i < (16 << l); i += TPB) kf[koff[l] + i] = kin[l][i];
            for (int i = tid; i < (2  << l); i += TPB) bss[boff[l] + i] = bin[l][i];
        }
    }

    // Load input chunk + halo (zero outside [0, NSEQ))
    {
        const float* xb = x + batch * NSEQ;
        const int base = s - 221;
        for (int i = tid; i < 2490; i += TPB) {
            const int g = base + i;
            bufA[i] = ((unsigned)g < (unsigned)NSEQ) ? xb[g] : 0.f;
        }
    }
    __syncthreads();

    // ---- analysis cascade (ping-pong) ----
    analysis_step<2490, 1242,  2, 16384>(bufA, bufB, kf + 0,   bss + 0,  (s >> 1) - 109);
    __syncthreads();
    analysis_step<1242,  618,  4,  8192>(bufB, bufA, kf + 16,  bss + 2,  (s >> 2) - 53);
    __syncthreads();
    analysis_step< 618,  306,  8,  4096>(bufA, bufB, kf + 48,  bss + 6,  (s >> 3) - 25);
    __syncthreads();
    analysis_step< 306,  150, 16,  2048>(bufB, bufA, kf + 112, bss + 14, (s >> 4) - 11);
    __syncthreads();
    analysis_step< 150,   72, 32,  1024>(bufA, bufB, kf + 240, bss + 30, (s >> 5) - 4);
    __syncthreads();

    // ---- synthesis cascade ----
    synth_step<  72,  136, 16,  2048>(bufB, bufA, kf + 240, (s >> 4) - 4);
    __syncthreads();
    synth_step< 136,  264,  8,  4096>(bufA, bufB, kf + 112, (s >> 3) - 4);
    __syncthreads();
    synth_step< 264,  520,  4,  8192>(bufB, bufA, kf + 48,  (s >> 2) - 4);
    __syncthreads();
    synth_step< 520, 1032,  2, 16384>(bufA, bufB, kf + 16,  (s >> 1) - 4);
    __syncthreads();

    // Final synthesis level (G=1): write central C0 samples straight to global
    {
        float* ob = out + batch * NSEQ + s;
        const float* __restrict__ y0 = bufB;          // level-1 recon, channel 0
        const float* __restrict__ y1 = bufB + 1032;   // channel 1
        for (int i = tid; i < C0; i += TPB) {
            const int nl = i + 4;                     // recon stored base = s/2 - 4
            const int j0 = (nl + 1) >> 1;
            const int kb = 7 - (nl & 1);
            float acc = 0.f;
#pragma unroll
            for (int q = 0; q < 4; ++q) {
                acc = fmaf(y0[j0 + q], kf[kb - 2 * q],     acc);
                acc = fmaf(y1[j0 + q], kf[8 + kb - 2 * q], acc);
            }
            ob[i] = acc;
        }
    }
}

extern "C" void kernel_launch(void* const* d_in, const int* in_sizes, int n_in,
                              void* d_out, int out_size, void* d_ws, size_t ws_size,
                              hipStream_t stream) {
    const int nbatch = in_sizes[0] / NSEQ;
    wpt_fused<<<dim3(nbatch * (NSEQ / C0)), dim3(TPB), 0, stream>>>(
        (const float*)d_in[0],
        (const float*)d_in[1], (const float*)d_in[2],
        (const float*)d_in[3], (const float*)d_in[4],
        (const float*)d_in[5],
        (const float*)d_in[6], (const float*)d_in[7],
        (const float*)d_in[8], (const float*)d_in[9],
        (const float*)d_in[10],
        (float*)d_out);
}

// Round 3
// 128.337 us; speedup vs baseline: 1.0458x; 1.0458x over previous
//
#include <hip/hip_runtime.h>

#define TPB 256

constexpr int NSEQ = 32768;
constexpr int C0   = 2048;   // output samples per block chunk

// Analysis halos: h_l = 2*h_{l+1}+3, h_5=4 -> {221,109,53,25,11,4}
// Valid lengths per level: A{1242,618,306,150,72}, padded P{1248,624,312,152,72}
// Row strides sized to the 16-float read window of the next level (exact fits):
//   S0=2504, SA={1256,632,312,152,72}; synthesis SS={136,264,520,1032}

__device__ __forceinline__ float gate(float y, float bb) {
    float e1 = __expf(-10.f * (y - bb));
    float e2 = __expf( 10.f * (y + bb));
    return __builtin_amdgcn_rcpf(1.f + e1) + __builtin_amdgcn_rcpf(1.f + e2);
}

// Analysis, register-blocked: each task = 4 consecutive outputs (i0..i0+3) for BOTH
// sibling output channels 2c, 2c+1 (they share the input window of channel c).
// Input window: in[c*Sin + 2*i0 .. +15] (16 floats, 4x b128, 32B aligned).
// out[ch*Sout + i0 .. +3] as float4. Mask outputs to [0,Nlev) (zero-pad semantics).
template<int Sin, int Sout, int P, int Gout, int Nlev>
__device__ __forceinline__ void analysis_r4(
    const float* __restrict__ in, float* __restrict__ out,
    const float* __restrict__ kf, const float* __restrict__ bias, int outBase)
{
    constexpr int TPC = P / 4;               // tasks per input channel
    constexpr int TOT = (Gout / 2) * TPC;
    for (int task = threadIdx.x; task < TOT; task += TPB) {
        const int c  = task / TPC;
        const int i0 = (task - c * TPC) * 4;

        float w[16];
        {
            const float4* ip = reinterpret_cast<const float4*>(in + c * Sin + 2 * i0);
            reinterpret_cast<float4*>(w)[0] = ip[0];
            reinterpret_cast<float4*>(w)[1] = ip[1];
            reinterpret_cast<float4*>(w)[2] = ip[2];
            reinterpret_cast<float4*>(w)[3] = ip[3];
        }
        float k0[8], k1[8];
        {
            const float4* kp = reinterpret_cast<const float4*>(kf + (2 * c) * 8);
            reinterpret_cast<float4*>(k0)[0] = kp[0];
            reinterpret_cast<float4*>(k0)[1] = kp[1];
            reinterpret_cast<float4*>(k1)[0] = kp[2];
            reinterpret_cast<float4*>(k1)[1] = kp[3];
        }
        const float b0 = bias[2 * c];
        const float b1 = bias[2 * c + 1];

        float o0[4], o1[4];
#pragma unroll
        for (int r = 0; r < 4; ++r) {
            float ya = 0.f, yb = 0.f;
#pragma unroll
            for (int t = 0; t < 8; ++t) {
                ya = fmaf(w[2 * r + t], k0[t], ya);
                yb = fmaf(w[2 * r + t], k1[t], yb);
            }
            const int m = outBase + i0 + r;
            const bool ok = ((unsigned)m < (unsigned)Nlev);
            o0[r] = ok ? ya * gate(ya, b0) : 0.f;
            o1[r] = ok ? yb * gate(yb, b1) : 0.f;
        }
        *reinterpret_cast<float4*>(out + (2 * c)     * Sout + i0) = *reinterpret_cast<float4*>(o0);
        *reinterpret_cast<float4*>(out + (2 * c + 1) * Sout + i0) = *reinterpret_cast<float4*>(o1);
    }
}

// Synthesis, register-blocked: each task = 8 consecutive outputs nl0..nl0+7 of group g.
// Reads y[2g], y[2g+1] floats [nl0/2 .. nl0/2+7] (2x b128 each, 16B lane stride).
// out[g*Sout + nl0 .. +7]; j_rel = (r+1)>>1, k index 7-(r&1)-2q.
template<int Sin, int Sout, int P, int Gout, int Nlev>
__device__ __forceinline__ void synth_r8(
    const float* __restrict__ in, float* __restrict__ out,
    const float* __restrict__ kf, int outBase)
{
    constexpr int TPG = P / 8;
    constexpr int TOT = Gout * TPG;
    for (int task = threadIdx.x; task < TOT; task += TPB) {
        const int g   = task / TPG;
        const int nl0 = (task - g * TPG) * 8;

        float ya[8], yb[8];
        {
            const float4* p0 = reinterpret_cast<const float4*>(in + (2 * g) * Sin + nl0 / 2);
            const float4* p1 = reinterpret_cast<const float4*>(in + (2 * g + 1) * Sin + nl0 / 2);
            reinterpret_cast<float4*>(ya)[0] = p0[0];
            reinterpret_cast<float4*>(ya)[1] = p0[1];
            reinterpret_cast<float4*>(yb)[0] = p1[0];
            reinterpret_cast<float4*>(yb)[1] = p1[1];
        }
        float k0[8], k1[8];
        {
            const float4* kp = reinterpret_cast<const float4*>(kf + (2 * g) * 8);
            reinterpret_cast<float4*>(k0)[0] = kp[0];
            reinterpret_cast<float4*>(k0)[1] = kp[1];
            reinterpret_cast<float4*>(k1)[0] = kp[2];
            reinterpret_cast<float4*>(k1)[1] = kp[3];
        }

        float o[8];
#pragma unroll
        for (int r = 0; r < 8; ++r) {
            const int jr = (r + 1) >> 1;
            const int kb = 7 - (r & 1);
            float acc = 0.f;
#pragma unroll
            for (int q = 0; q < 4; ++q) {
                acc = fmaf(ya[jr + q], k0[kb - 2 * q], acc);
                acc = fmaf(yb[jr + q], k1[kb - 2 * q], acc);
            }
            const int m = outBase + nl0 + r;
            o[r] = ((unsigned)m < (unsigned)Nlev) ? acc : 0.f;
        }
        float* op = out + g * Sout + nl0;
        *reinterpret_cast<float4*>(op)     = *reinterpret_cast<float4*>(o);
        *reinterpret_cast<float4*>(op + 4) = *reinterpret_cast<float4*>(o + 4);
    }
}

__global__ __launch_bounds__(TPB) void wpt_fused(
    const float* __restrict__ x,
    const float* __restrict__ K1, const float* __restrict__ K2,
    const float* __restrict__ K3, const float* __restrict__ K4,
    const float* __restrict__ K5,
    const float* __restrict__ B1, const float* __restrict__ B2,
    const float* __restrict__ B3, const float* __restrict__ B4,
    const float* __restrict__ B5,
    float* __restrict__ out)
{
    __shared__ __align__(16) float bufA[2528];
    __shared__ __align__(16) float bufB[2512];
    __shared__ __align__(16) float kf[496];
    __shared__ float bss[62];

    const int tid   = threadIdx.x;
    const int batch = blockIdx.x >> 4;
    const int cid   = blockIdx.x & 15;
    const int s     = cid * C0;

    // Stage filters + biases
    {
        const float* kin[5] = {K1, K2, K3, K4, K5};
        const float* bin[5] = {B1, B2, B3, B4, B5};
        const int koff[5] = {0, 16, 48, 112, 240};
        const int boff[5] = {0, 2, 6, 14, 30};
#pragma unroll
        for (int l = 0; l < 5; ++l) {
            for (int i = tid; i < (16 << l); i += TPB) kf[koff[l] + i] = kin[l][i];
            for (int i = tid; i < (2  << l); i += TPB) bss[boff[l] + i] = bin[l][i];
        }
    }

    // Load input chunk + halo into bufA[0..2503]; zero outside valid range
    {
        const float* xb = x + batch * NSEQ;
        const int base = s - 221;
        for (int i = tid; i < 2504; i += TPB) {
            const int g = base + i;
            bufA[i] = (i < 2490 && (unsigned)g < (unsigned)NSEQ) ? xb[g] : 0.f;
        }
    }
    __syncthreads();

    // ---- analysis cascade ----
    analysis_r4<2504, 1256, 1248,  2, 16384>(bufA, bufB, kf + 0,   bss + 0,  (s >> 1) - 109);
    __syncthreads();
    analysis_r4<1256,  632,  624,  4,  8192>(bufB, bufA, kf + 16,  bss + 2,  (s >> 2) - 53);
    __syncthreads();
    analysis_r4< 632,  312,  312,  8,  4096>(bufA, bufB, kf + 48,  bss + 6,  (s >> 3) - 25);
    __syncthreads();
    analysis_r4< 312,  152,  152, 16,  2048>(bufB, bufA, kf + 112, bss + 14, (s >> 4) - 11);
    __syncthreads();
    analysis_r4< 152,   72,   72, 32,  1024>(bufA, bufB, kf + 240, bss + 30, (s >> 5) - 4);
    __syncthreads();

    // ---- synthesis cascade ----
    synth_r8<  72,  136,  136, 16,  2048>(bufB, bufA, kf + 240, (s >> 4) - 4);
    __syncthreads();
    synth_r8< 136,  264,  264,  8,  4096>(bufA, bufB, kf + 112, (s >> 3) - 4);
    __syncthreads();
    synth_r8< 264,  520,  520,  4,  8192>(bufB, bufA, kf + 48,  (s >> 2) - 4);
    __syncthreads();
    synth_r8< 520, 1032, 1032,  2, 16384>(bufA, bufB, kf + 16,  (s >> 1) - 4);
    __syncthreads();

    // ---- final synthesis level (G=1), straight to global ----
    // j_local = ((i+1)>>1) + 2 + q, k index 7-(i&1)-2q; read 12 floats per channel.
    {
        float* ob = out + batch * NSEQ + s;
        const int i0 = tid * 8;              // 256 tasks exactly
        float ya[12], yb[12];
        {
            const float4* p0 = reinterpret_cast<const float4*>(bufB + i0 / 2);
            const float4* p1 = reinterpret_cast<const float4*>(bufB + 1032 + i0 / 2);
            reinterpret_cast<float4*>(ya)[0] = p0[0];
            reinterpret_cast<float4*>(ya)[1] = p0[1];
            reinterpret_cast<float4*>(ya)[2] = p0[2];
            reinterpret_cast<float4*>(yb)[0] = p1[0];
            reinterpret_cast<float4*>(yb)[1] = p1[1];
            reinterpret_cast<float4*>(yb)[2] = p1[2];
        }
        float k0[8], k1[8];
        {
            const float4* kp = reinterpret_cast<const float4*>(kf);
            reinterpret_cast<float4*>(k0)[0] = kp[0];
            reinterpret_cast<float4*>(k0)[1] = kp[1];
            reinterpret_cast<float4*>(k1)[0] = kp[2];
            reinterpret_cast<float4*>(k1)[1] = kp[3];
        }
        float o[8];
#pragma unroll
        for (int r = 0; r < 8; ++r) {
            const int jr = ((r + 1) >> 1) + 2;
            const int kb = 7 - (r & 1);
            float acc = 0.f;
#pragma unroll
            for (int q = 0; q < 4; ++q) {
                acc = fmaf(ya[jr + q], k0[kb - 2 * q], acc);
                acc = fmaf(yb[jr + q], k1[kb - 2 * q], acc);
            }
            o[r] = acc;
        }
        *reinterpret_cast<float4*>(ob + i0)     = *reinterpret_cast<float4*>(o);
        *reinterpret_cast<float4*>(ob + i0 + 4) = *reinterpret_cast<float4*>(o + 4);
    }
}

extern "C" void kernel_launch(void* const* d_in, const int* in_sizes, int n_in,
                              void* d_out, int out_size, void* d_ws, size_t ws_size,
                              hipStream_t stream) {
    const int nbatch = in_sizes[0] / NSEQ;
    wpt_fused<<<dim3(nbatch * (NSEQ / C0)), dim3(TPB), 0, stream>>>(
        (const float*)d_in[0],
        (const float*)d_in[1], (const float*)d_in[2],
        (const float*)d_in[3], (const float*)d_in[4],
        (const float*)d_in[5],
        (const float*)d_in[6], (const float*)d_in[7],
        (const float*)d_in[8], (const float*)d_in[9],
        (const float*)d_in[10],
        (float*)d_out);
}

// Round 4
// 122.480 us; speedup vs baseline: 1.0958x; 1.0478x over previous
//
#include <hip/hip_runtime.h>

#define TPB 256

constexpr int NSEQ = 32768;
constexpr int C0   = 2048;   // output samples per block chunk

// Analysis halos: h_l = 2*h_{l+1}+3, h_5=4 -> {221,109,53,25,11,4}
// Valid per-channel lengths: {1242,618,306,150,72}; padded P: {1248,624,312,152,72}
// Parity storage (levels 0..4): per channel [E | O], each length LE = P+4:
//   LE: {1252, 628, 316, 156, 76}.  Level-5 output contiguous, stride 72.
// Synthesis buffers: halo 4, strides {136,264,520,1032}.

__device__ __forceinline__ float gate(float y, float bb) {
    float e1 = __expf(-10.f * (y - bb));
    float e2 = __expf( 10.f * (y + bb));
    return __builtin_amdgcn_rcpf(1.f + e1) + __builtin_amdgcn_rcpf(1.f + e2);
}

// Analysis level, parity in -> parity out.
// Task = 4 consecutive outputs (i0..i0+3) for sibling channels 2c,2c+1.
// in[2i+t] == E[i + t/2] (t even) / O[i + (t-1)/2] (t odd).
// Reads E[i0..i0+7], O[i0..i0+7] (2x b128 each, 16B lane stride, dense).
// Writes per channel: E[j0..j0+1], O[j0..j0+1] as float2 (8B lane stride, dense).
template<int LEin, int LEout, int P, int Gout, int Nlev>
__device__ __forceinline__ void analysis_pp(
    const float* __restrict__ in, float* __restrict__ out,
    const float* __restrict__ kf, const float* __restrict__ bias, int outBase)
{
    constexpr int TPC = P / 4;
    constexpr int TOT = (Gout / 2) * TPC;
    for (int task = threadIdx.x; task < TOT; task += TPB) {
        const int c  = task / TPC;
        const int i0 = (task - c * TPC) * 4;

        const float* ep = in + c * (2 * LEin) + i0;
        const float* op = ep + LEin;
        float e[8], o[8];
        reinterpret_cast<float4*>(e)[0] = *reinterpret_cast<const float4*>(ep);
        reinterpret_cast<float4*>(e)[1] = *reinterpret_cast<const float4*>(ep + 4);
        reinterpret_cast<float4*>(o)[0] = *reinterpret_cast<const float4*>(op);
        reinterpret_cast<float4*>(o)[1] = *reinterpret_cast<const float4*>(op + 4);

        float k0[8], k1[8];
        {
            const float4* kp = reinterpret_cast<const float4*>(kf + (2 * c) * 8);
            reinterpret_cast<float4*>(k0)[0] = kp[0];
            reinterpret_cast<float4*>(k0)[1] = kp[1];
            reinterpret_cast<float4*>(k1)[0] = kp[2];
            reinterpret_cast<float4*>(k1)[1] = kp[3];
        }
        const float b0 = bias[2 * c];
        const float b1 = bias[2 * c + 1];

        float v0[4], v1[4];
#pragma unroll
        for (int r = 0; r < 4; ++r) {
            float ya = 0.f, yb = 0.f;
#pragma unroll
            for (int u = 0; u < 4; ++u) {
                ya = fmaf(e[r + u], k0[2 * u], ya);
                ya = fmaf(o[r + u], k0[2 * u + 1], ya);
                yb = fmaf(e[r + u], k1[2 * u], yb);
                yb = fmaf(o[r + u], k1[2 * u + 1], yb);
            }
            const int m = outBase + i0 + r;
            const bool ok = ((unsigned)m < (unsigned)Nlev);
            v0[r] = ok ? ya * gate(ya, b0) : 0.f;
            v1[r] = ok ? yb * gate(yb, b1) : 0.f;
        }

        const int j0 = i0 >> 1;
        float* ob0 = out + (2 * c) * (2 * LEout);
        float* ob1 = ob0 + 2 * LEout;
        *reinterpret_cast<float2*>(ob0 + j0)         = make_float2(v0[0], v0[2]);
        *reinterpret_cast<float2*>(ob0 + LEout + j0) = make_float2(v0[1], v0[3]);
        *reinterpret_cast<float2*>(ob1 + j0)         = make_float2(v1[0], v1[2]);
        *reinterpret_cast<float2*>(ob1 + LEout + j0) = make_float2(v1[1], v1[3]);
    }
}

// Analysis level, parity in -> contiguous out (level 5, feeds synthesis).
template<int LEin, int Sout, int P, int Gout, int Nlev>
__device__ __forceinline__ void analysis_pn(
    const float* __restrict__ in, float* __restrict__ out,
    const float* __restrict__ kf, const float* __restrict__ bias, int outBase)
{
    constexpr int TPC = P / 4;
    constexpr int TOT = (Gout / 2) * TPC;
    for (int task = threadIdx.x; task < TOT; task += TPB) {
        const int c  = task / TPC;
        const int i0 = (task - c * TPC) * 4;

        const float* ep = in + c * (2 * LEin) + i0;
        const float* op = ep + LEin;
        float e[8], o[8];
        reinterpret_cast<float4*>(e)[0] = *reinterpret_cast<const float4*>(ep);
        reinterpret_cast<float4*>(e)[1] = *reinterpret_cast<const float4*>(ep + 4);
        reinterpret_cast<float4*>(o)[0] = *reinterpret_cast<const float4*>(op);
        reinterpret_cast<float4*>(o)[1] = *reinterpret_cast<const float4*>(op + 4);

        float k0[8], k1[8];
        {
            const float4* kp = reinterpret_cast<const float4*>(kf + (2 * c) * 8);
            reinterpret_cast<float4*>(k0)[0] = kp[0];
            reinterpret_cast<float4*>(k0)[1] = kp[1];
            reinterpret_cast<float4*>(k1)[0] = kp[2];
            reinterpret_cast<float4*>(k1)[1] = kp[3];
        }
        const float b0 = bias[2 * c];
        const float b1 = bias[2 * c + 1];

        float v0[4], v1[4];
#pragma unroll
        for (int r = 0; r < 4; ++r) {
            float ya = 0.f, yb = 0.f;
#pragma unroll
            for (int u = 0; u < 4; ++u) {
                ya = fmaf(e[r + u], k0[2 * u], ya);
                ya = fmaf(o[r + u], k0[2 * u + 1], ya);
                yb = fmaf(e[r + u], k1[2 * u], yb);
                yb = fmaf(o[r + u], k1[2 * u + 1], yb);
            }
            const int m = outBase + i0 + r;
            const bool ok = ((unsigned)m < (unsigned)Nlev);
            v0[r] = ok ? ya * gate(ya, b0) : 0.f;
            v1[r] = ok ? yb * gate(yb, b1) : 0.f;
        }
        *reinterpret_cast<float4*>(out + (2 * c)     * Sout + i0) = *reinterpret_cast<float4*>(v0);
        *reinterpret_cast<float4*>(out + (2 * c + 1) * Sout + i0) = *reinterpret_cast<float4*>(v1);
    }
}

// Synthesis (transposed conv): task = 8 consecutive outputs nl0..nl0+7 of group g.
// Reads y[2g], y[2g+1] at [nl0/2 .. +7] (2x b128 each, 16B lane stride, dense).
template<int Sin, int Sout, int P, int Gout, int Nlev>
__device__ __forceinline__ void synth_r8(
    const float* __restrict__ in, float* __restrict__ out,
    const float* __restrict__ kf, int outBase)
{
    constexpr int TPG = P / 8;
    constexpr int TOT = Gout * TPG;
    for (int task = threadIdx.x; task < TOT; task += TPB) {
        const int g   = task / TPG;
        const int nl0 = (task - g * TPG) * 8;

        float ya[8], yb[8];
        {
            const float4* p0 = reinterpret_cast<const float4*>(in + (2 * g) * Sin + nl0 / 2);
            const float4* p1 = reinterpret_cast<const float4*>(in + (2 * g + 1) * Sin + nl0 / 2);
            reinterpret_cast<float4*>(ya)[0] = p0[0];
            reinterpret_cast<float4*>(ya)[1] = p0[1];
            reinterpret_cast<float4*>(yb)[0] = p1[0];
            reinterpret_cast<float4*>(yb)[1] = p1[1];
        }
        float k0[8], k1[8];
        {
            const float4* kp = reinterpret_cast<const float4*>(kf + (2 * g) * 8);
            reinterpret_cast<float4*>(k0)[0] = kp[0];
            reinterpret_cast<float4*>(k0)[1] = kp[1];
            reinterpret_cast<float4*>(k1)[0] = kp[2];
            reinterpret_cast<float4*>(k1)[1] = kp[3];
        }

        float o[8];
#pragma unroll
        for (int r = 0; r < 8; ++r) {
            const int jr = (r + 1) >> 1;
            const int kb = 7 - (r & 1);
            float acc = 0.f;
#pragma unroll
            for (int q = 0; q < 4; ++q) {
                acc = fmaf(ya[jr + q], k0[kb - 2 * q], acc);
                acc = fmaf(yb[jr + q], k1[kb - 2 * q], acc);
            }
            const int m = outBase + nl0 + r;
            o[r] = ((unsigned)m < (unsigned)Nlev) ? acc : 0.f;
        }
        float* opt = out + g * Sout + nl0;
        *reinterpret_cast<float4*>(opt)     = *reinterpret_cast<float4*>(o);
        *reinterpret_cast<float4*>(opt + 4) = *reinterpret_cast<float4*>(o + 4);
    }
}

__global__ __launch_bounds__(TPB) void wpt_fused(
    const float* __restrict__ x,
    const float* __restrict__ K1, const float* __restrict__ K2,
    const float* __restrict__ K3, const float* __restrict__ K4,
    const float* __restrict__ K5,
    const float* __restrict__ B1, const float* __restrict__ B2,
    const float* __restrict__ B3, const float* __restrict__ B4,
    const float* __restrict__ B5,
    float* __restrict__ out)
{
    __shared__ __align__(16) float bufA[2528];
    __shared__ __align__(16) float bufB[2512];
    __shared__ __align__(16) float kf[496];
    __shared__ float bss[62];

    const int tid   = threadIdx.x;
    const int batch = blockIdx.x >> 4;
    const int cid   = blockIdx.x & 15;
    const int s     = cid * C0;

    // Stage filters + biases
    {
        const float* kin[5] = {K1, K2, K3, K4, K5};
        const float* bin[5] = {B1, B2, B3, B4, B5};
        const int koff[5] = {0, 16, 48, 112, 240};
        const int boff[5] = {0, 2, 6, 14, 30};
#pragma unroll
        for (int l = 0; l < 5; ++l) {
            for (int i = tid; i < (16 << l); i += TPB) kf[koff[l] + i] = kin[l][i];
            for (int i = tid; i < (2  << l); i += TPB) bss[boff[l] + i] = bin[l][i];
        }
    }

    // Load input chunk + halo, parity-split: bufA[0..1251]=E0, bufA[1252..2503]=O0.
    // Element i of the window (global g = s-221+i): E0[j]=x[2j], O0[j]=x[2j+1].
    // Valid window elements: i < 2490 and g in [0, NSEQ).
    {
        const float* xb = x + batch * NSEQ;
        const int base = s - 221;
        for (int j = tid; j < 1252; j += TPB) {
            const int g0 = base + 2 * j;
            const int g1 = g0 + 1;
            const bool okj = (j < 1245);     // 2j, 2j+1 < 2490
            bufA[j]        = (okj && (unsigned)g0 < (unsigned)NSEQ) ? xb[g0] : 0.f;
            bufA[1252 + j] = (okj && (unsigned)g1 < (unsigned)NSEQ) ? xb[g1] : 0.f;
        }
    }
    __syncthreads();

    // ---- analysis cascade (parity ping-pong) ----
    analysis_pp<1252, 628, 1248,  2, 16384>(bufA, bufB, kf + 0,   bss + 0,  (s >> 1) - 109);
    __syncthreads();
    analysis_pp< 628, 316,  624,  4,  8192>(bufB, bufA, kf + 16,  bss + 2,  (s >> 2) - 53);
    __syncthreads();
    analysis_pp< 316, 156,  312,  8,  4096>(bufA, bufB, kf + 48,  bss + 6,  (s >> 3) - 25);
    __syncthreads();
    analysis_pp< 156,  76,  152, 16,  2048>(bufB, bufA, kf + 112, bss + 14, (s >> 4) - 11);
    __syncthreads();
    analysis_pn<  76,  72,   72, 32,  1024>(bufA, bufB, kf + 240, bss + 30, (s >> 5) - 4);
    __syncthreads();

    // ---- synthesis cascade ----
    synth_r8<  72,  136,  136, 16,  2048>(bufB, bufA, kf + 240, (s >> 4) - 4);
    __syncthreads();
    synth_r8< 136,  264,  264,  8,  4096>(bufA, bufB, kf + 112, (s >> 3) - 4);
    __syncthreads();
    synth_r8< 264,  520,  520,  4,  8192>(bufB, bufA, kf + 48,  (s >> 2) - 4);
    __syncthreads();
    synth_r8< 520, 1032, 1032,  2, 16384>(bufA, bufB, kf + 16,  (s >> 1) - 4);
    __syncthreads();

    // ---- final synthesis level (G=1), straight to global ----
    {
        float* ob = out + batch * NSEQ + s;
        const int i0 = tid * 8;              // 256 tasks exactly
        float ya[12], yb[12];
        {
            const float4* p0 = reinterpret_cast<const float4*>(bufB + i0 / 2);
            const float4* p1 = reinterpret_cast<const float4*>(bufB + 1032 + i0 / 2);
            reinterpret_cast<float4*>(ya)[0] = p0[0];
            reinterpret_cast<float4*>(ya)[1] = p0[1];
            reinterpret_cast<float4*>(ya)[2] = p0[2];
            reinterpret_cast<float4*>(yb)[0] = p1[0];
            reinterpret_cast<float4*>(yb)[1] = p1[1];
            reinterpret_cast<float4*>(yb)[2] = p1[2];
        }
        float k0[8], k1[8];
        {
            const float4* kp = reinterpret_cast<const float4*>(kf);
            reinterpret_cast<float4*>(k0)[0] = kp[0];
            reinterpret_cast<float4*>(k0)[1] = kp[1];
            reinterpret_cast<float4*>(k1)[0] = kp[2];
            reinterpret_cast<float4*>(k1)[1] = kp[3];
        }
        float o[8];
#pragma unroll
        for (int r = 0; r < 8; ++r) {
            const int jr = ((r + 1) >> 1) + 2;
            const int kb = 7 - (r & 1);
            float acc = 0.f;
#pragma unroll
            for (int q = 0; q < 4; ++q) {
                acc = fmaf(ya[jr + q], k0[kb - 2 * q], acc);
                acc = fmaf(yb[jr + q], k1[kb - 2 * q], acc);
            }
            o[r] = acc;
        }
        *reinterpret_cast<float4*>(ob + i0)     = *reinterpret_cast<float4*>(o);
        *reinterpret_cast<float4*>(ob + i0 + 4) = *reinterpret_cast<float4*>(o + 4);
    }
}

extern "C" void kernel_launch(void* const* d_in, const int* in_sizes, int n_in,
                              void* d_out, int out_size, void* d_ws, size_t ws_size,
                              hipStream_t stream) {
    const int nbatch = in_sizes[0] / NSEQ;
    wpt_fused<<<dim3(nbatch * (NSEQ / C0)), dim3(TPB), 0, stream>>>(
        (const float*)d_in[0],
        (const float*)d_in[1], (const float*)d_in[2],
        (const float*)d_in[3], (const float*)d_in[4],
        (const float*)d_in[5],
        (const float*)d_in[6], (const float*)d_in[7],
        (const float*)d_in[8], (const float*)d_in[9],
        (const float*)d_in[10],
        (float*)d_out);
}